// Round 5
// baseline (768.707 us; speedup 1.0000x reference)
//
#include <hip/hip_runtime.h>

typedef __attribute__((ext_vector_type(8))) short bf16x8;
typedef __attribute__((ext_vector_type(4))) short bf16x4;
typedef __attribute__((ext_vector_type(4))) float f32x4;
typedef __attribute__((ext_vector_type(2))) float f32x2;

#define BATCH 2
#define CH    512
#define NPIX  4096
#define NSP   2
#define SPK   2048   // keys per split
#define KT    32     // keys per tile

__device__ __forceinline__ unsigned short f2b(float f) {
    unsigned int u; __builtin_memcpy(&u, &f, 4);
    u = u + 0x7FFFu + ((u >> 16) & 1u);   // RNE
    return (unsigned short)(u >> 16);
}
__device__ __forceinline__ float b2f(unsigned short h) {
    unsigned int u = ((unsigned int)h) << 16;
    float f; __builtin_memcpy(&f, &u, 4);
    return f;
}
// async 16B/lane global->LDS (wave-uniform LDS base, per-lane global src)
__device__ __forceinline__ void gll16(void* lds, const void* g) {
    __builtin_amdgcn_global_load_lds(
        (const __attribute__((address_space(1))) void*)g,
        (__attribute__((address_space(3))) void*)lds, 16, 0, 0);
}

// ---------------------------------------------------------------- fp32 -> bf16 weight convert
__global__ __launch_bounds__(256) void convert_kernel(
    const float* __restrict__ qkv_w, const float* __restrict__ proj_w,
    unsigned short* __restrict__ wbf)
{
    int i = blockIdx.x * 256 + threadIdx.x;            // grid covers 1048576
    float v = (i < 786432) ? qkv_w[i] : proj_w[i - 786432];
    wbf[i] = f2b(v);
}

// ---------------------------------------------------------------- GN stats (2-stage, parallel)
__global__ __launch_bounds__(256) void stats1_kernel(
    const float* __restrict__ x, f32x2* __restrict__ part)
{
    int id = blockIdx.x;            // 256 blocks: bg*4 + quarter
    int bg = id >> 2, q = id & 3;
    int b = bg >> 5, g = bg & 31;
    const float* xp = x + ((size_t)b * CH + (size_t)g * 16 + q * 4) * NPIX;
    float s = 0.f, ss = 0.f;
    for (int i = threadIdx.x; i < 4 * NPIX; i += 256) {
        float v = xp[i]; s += v; ss += v * v;
    }
    for (int off = 32; off; off >>= 1) {
        s  += __shfl_down(s,  off, 64);
        ss += __shfl_down(ss, off, 64);
    }
    __shared__ float red[2][4];
    int wv = threadIdx.x >> 6;
    if ((threadIdx.x & 63) == 0) { red[0][wv] = s; red[1][wv] = ss; }
    __syncthreads();
    if (threadIdx.x == 0) {
        s  = red[0][0] + red[0][1] + red[0][2] + red[0][3];
        ss = red[1][0] + red[1][1] + red[1][2] + red[1][3];
        part[id] = (f32x2){s, ss};
    }
}

__global__ __launch_bounds__(64) void stats2_kernel(
    const f32x2* __restrict__ part, float* __restrict__ stats)
{
    int t = threadIdx.x;            // 64 = b*32+g
    float s = 0.f, ss = 0.f;
    #pragma unroll
    for (int q = 0; q < 4; q++) { f32x2 p = part[t * 4 + q]; s += p[0]; ss += p[1]; }
    const float inv = 1.f / (16 * NPIX);
    float mean = s * inv;
    float var  = ss * inv - mean * mean;
    stats[t * 2 + 0] = mean;
    stats[t * 2 + 1] = rsqrtf(var + 1e-6f);
}

// ---------------------------------------------------------------- GroupNorm materialize (bf16)
__global__ __launch_bounds__(256) void hn_kernel(
    const float* __restrict__ x,
    const float* __restrict__ gamma, const float* __restrict__ beta,
    const float* __restrict__ stats,
    unsigned short* __restrict__ hnb)    // [b][c][n] bf16
{
    size_t i = ((size_t)blockIdx.x * 256 + threadIdx.x) * 8;   // grid 2048
    int b = (int)(i >> 21), c = (int)((i >> 12) & 511);
    float mean = stats[(b * 32 + (c >> 4)) * 2 + 0];
    float rstd = stats[(b * 32 + (c >> 4)) * 2 + 1];
    float ga = gamma[c] * rstd;
    float be = beta[c] - mean * ga;
    f32x4 v0 = *(const f32x4*)(x + i);
    f32x4 v1 = *(const f32x4*)(x + i + 4);
    bf16x8 o;
    o[0] = f2b(v0[0]*ga+be); o[1] = f2b(v0[1]*ga+be);
    o[2] = f2b(v0[2]*ga+be); o[3] = f2b(v0[3]*ga+be);
    o[4] = f2b(v1[0]*ga+be); o[5] = f2b(v1[1]*ga+be);
    o[6] = f2b(v1[2]*ga+be); o[7] = f2b(v1[3]*ga+be);
    *(bf16x8*)(hnb + i) = o;
}

// ---------------------------------------------------------------- Q/K/V GEMM (64-pixel tiles)
// grid (64, 2, 3) = 384 blocks, 2 blocks/CU. third 0->Q (scaled), 1->K, 2->V.
__global__ __launch_bounds__(256, 2) void qkv_kernel(
    const unsigned short* __restrict__ hnb,  // [b][c][n] bf16
    const unsigned short* __restrict__ wbf,  // bf16 qkv_w [1536][512]
    const float* __restrict__ bias,
    unsigned short* __restrict__ Q,          // [b][n][c] pre-scaled
    unsigned short* __restrict__ K,          // [b][n][c]
    unsigned short* __restrict__ V)          // [b][c][n]
{
    __shared__ unsigned short hn[64][520];
    int b     = blockIdx.y;
    int third = blockIdx.z;
    int m0    = blockIdx.x * 64;
    int tid = threadIdx.x;
    {   // stage hn: p = tid&63 (pixel), cg = tid>>6 (4 channel slots)
        const unsigned short* hb = hnb + (size_t)b * CH * NPIX + m0;
        int p = tid & 63, cg = tid >> 6;
        for (int c0 = 0; c0 < CH; c0 += 4) {
            int c = c0 + cg;
            hn[p][c] = hb[(size_t)c * NPIX + p];
        }
    }
    __syncthreads();

    int wv = tid >> 6, lane = tid & 63, ln = lane & 15, quad = lane >> 4;
    const float scale = 0.04419417382415922f;  // 512^-0.5
    #pragma unroll
    for (int nt = 0; nt < 8; nt++) {
        int o = nt * 64 + wv * 16 + ln;            // [0, 512)
        int row = third * 512 + o;
        const unsigned short* bp = wbf + (size_t)row * CH + quad * 8;
        bf16x8 wf[16];
        #pragma unroll
        for (int k = 0; k < 16; k++) wf[k] = *(const bf16x8*)(bp + k * 32);
        float bi = bias[row];
        #pragma unroll
        for (int qt = 0; qt < 4; qt++) {
            f32x4 acc = {0.f, 0.f, 0.f, 0.f};
            #pragma unroll
            for (int k = 0; k < 16; k++) {
                bf16x8 a = *(const bf16x8*)(&hn[qt * 16 + ln][quad * 8 + k * 32]);
                acc = __builtin_amdgcn_mfma_f32_16x16x32_bf16(a, wf[k], acc, 0, 0, 0);
            }
            int m = m0 + qt * 16 + quad * 4;
            if (third == 0) {
                #pragma unroll
                for (int r = 0; r < 4; r++)
                    Q[((size_t)b * NPIX + m + r) * CH + o] = f2b((acc[r] + bi) * scale);
            } else if (third == 1) {
                #pragma unroll
                for (int r = 0; r < 4; r++)
                    K[((size_t)b * NPIX + m + r) * CH + o] = f2b(acc[r] + bi);
            } else {
                bf16x4 pk;
                #pragma unroll
                for (int r = 0; r < 4; r++) pk[r] = f2b(acc[r] + bi);
                *(bf16x4*)(V + ((size_t)b * CH + o) * NPIX + m) = pk;
            }
        }
    }
}

// ---------------------------------------------------------------- attention: in-register flash
// 512 blocks x 256 thr (4 waves), 2 blocks/CU (LDS = K-dbuf 64KB only).
// bid&7 = XCD -> (b,sp): per-XCD K+V working set = 4MB (= L2).
// Swapped QK^T: S = mfma(K,Q) => lane holds 8 S-values of ONE query (ln),
// keys {quad*4+r} u {16+quad*4+r}. Softmax fully in registers (defer-max THR=8).
// PV key order pi-permuted: V read direct from global as two contiguous 8B runs
// per 16-ch block (round-3-style conflict-free pattern) -> no V LDS at all.
// Per iter: vmcnt(40)+bar | S | softmax | PV | lgkm+bar.  No vmcnt(0) in loop.
__global__ __launch_bounds__(256, 2) void attn_kernel(
    const unsigned short* __restrict__ Qg,   // [b][n][c] bf16, pre-scaled
    const unsigned short* __restrict__ Kg,   // [b][n][c]
    const unsigned short* __restrict__ Vg,   // [b][c][n]
    unsigned short* __restrict__ Opart,      // [b][sp][n][c] bf16 numerators
    float* __restrict__ ml)                  // [b][sp][n][2] f32
{
    // LDS: K dbuf 2x32KB ([32 key-rows][64 chunks16B], chunk p holds global chunk p^(row&7))
    __shared__ __align__(16) char sm[65536];
    char* const KB0 = sm;
    char* const KB1 = sm + 32768;

    int bid = blockIdx.x;
    int xcd = bid & 7;
    int b  = (xcd >> 1) & 1;
    int sp = xcd & 1;
    int q0 = (((bid >> 3) << 1) | (xcd >> 2)) << 5;   // 128 query-tiles of 32
    int tid = threadIdx.x;
    int wv = tid >> 6, lane = tid & 63, ln = lane & 15, quad = lane >> 4;
    int qg = wv & 1, cs = wv >> 1;           // query group (16q), channel half (256c)

    const unsigned short* K = Kg + ((size_t)b * NPIX + (size_t)sp * SPK) * CH;
    const unsigned short* V = Vg + (size_t)b * CH * NPIX + (size_t)sp * SPK;
    const unsigned short* Qp = Qg + ((size_t)(b * NPIX + q0 + qg * 16)) * CH;

    // ---- K stage: 8 rows per wave; row r, LDS chunk p holds global chunk p^(r&7)
    auto stageK = [&](char* buf, int kb) {
        #pragma unroll
        for (int j = 0; j < 8; j++) {
            int r = wv * 8 + j;
            gll16(buf + r * 1024,
                  K + (size_t)(kb + r) * CH + ((lane ^ j) << 3));
        }
    };

    // ---- prologue: stage tile 0, load persistent Q fragments
    stageK(KB0, 0);
    bf16x8 qf[16];
    #pragma unroll
    for (int kt = 0; kt < 16; kt++)
        qf[kt] = *(const bf16x8*)(Qp + (size_t)ln * CH + kt * 32 + quad * 8);

    // per-lane K LDS read base (swizzle folded: chunk = (kt*4+quad)^(ln&7))
    const int BK = ln * 1024 + ((quad ^ (ln & 3)) << 4) + (((ln >> 2) & 1) << 6);

    f32x4 O[16];
    #pragma unroll
    for (int i = 0; i < 16; i++) O[i] = (f32x4){0.f, 0.f, 0.f, 0.f};
    float m_reg = -1e30f, l_reg = 0.f;

    const unsigned short* vb = V + (size_t)(cs * 256 + ln) * NPIX;

    for (int it = 0; it < SPK / KT; ++it) {
        int kb = it << 5;
        char* const KBc = (it & 1) ? KB1 : KB0;
        char* const KBn = (it & 1) ? KB0 : KB1;

        // (a) V loads for this tile (pi order: keys quad*4.. and 16+quad*4..)
        bf16x4 vlo[16], vhi[16];
        #pragma unroll
        for (int ct = 0; ct < 16; ct++) {
            const unsigned short* p = vb + (size_t)ct * 16 * NPIX + kb;
            vlo[ct] = *(const bf16x4*)(p + quad * 4);
            vhi[ct] = *(const bf16x4*)(p + 16 + quad * 4);
        }

        // (b) async-stage next K tile (last iter wraps: harmless dummy)
        stageK(KBn, ((it + 1) * KT) & (SPK - 1));

        // (c) queue = [stage(cur) 8][V 32][stage(next) 8] = 48; oldest-first:
        //     vmcnt(40) ==> stage(cur) landed; V + stage(next) stay in flight.
        asm volatile("s_waitcnt vmcnt(40)" ::: "memory");
        __builtin_amdgcn_s_barrier();

        // (d) S = mfma(K, Q): lane -> query ln; Sa keys quad*4+r, Sb 16+quad*4+r
        const char* kE = KBc + BK;
        const char* kO = KBc + (BK ^ 64);
        f32x4 Sa = {0.f,0.f,0.f,0.f}, Sb = {0.f,0.f,0.f,0.f};
        __builtin_amdgcn_s_setprio(1);
        #pragma unroll
        for (int kt = 0; kt < 16; kt++) {
            const char* p = (kt & 1) ? kO : kE;
            bf16x8 k0 = *(const bf16x8*)(p + (kt >> 1) * 128);
            bf16x8 k1 = *(const bf16x8*)(p + (kt >> 1) * 128 + 16384);
            Sa = __builtin_amdgcn_mfma_f32_16x16x32_bf16(k0, qf[kt], Sa, 0, 0, 0);
            Sb = __builtin_amdgcn_mfma_f32_16x16x32_bf16(k1, qf[kt], Sb, 0, 0, 0);
        }
        __builtin_amdgcn_s_setprio(0);

        // (e) in-register online softmax with defer-max (THR=8)
        float mx = fmaxf(fmaxf(fmaxf(Sa[0],Sa[1]), fmaxf(Sa[2],Sa[3])),
                         fmaxf(fmaxf(Sb[0],Sb[1]), fmaxf(Sb[2],Sb[3])));
        mx = fmaxf(mx, __shfl_xor(mx, 16, 64));
        mx = fmaxf(mx, __shfl_xor(mx, 32, 64));
        if (!__all(mx <= m_reg + 8.f)) {
            float mnew  = fmaxf(m_reg, mx);
            float alpha = __expf(m_reg - mnew);
            l_reg *= alpha;
            #pragma unroll
            for (int ct = 0; ct < 16; ct++) {
                #pragma unroll
                for (int r = 0; r < 4; r++) O[ct][r] *= alpha;
            }
            m_reg = mnew;
        }
        float e0 = __expf(Sa[0]-m_reg), e1 = __expf(Sa[1]-m_reg);
        float e2 = __expf(Sa[2]-m_reg), e3 = __expf(Sa[3]-m_reg);
        float e4 = __expf(Sb[0]-m_reg), e5 = __expf(Sb[1]-m_reg);
        float e6 = __expf(Sb[2]-m_reg), e7 = __expf(Sb[3]-m_reg);
        float ts = ((e0+e1)+(e2+e3)) + ((e4+e5)+(e6+e7));
        ts += __shfl_xor(ts, 16, 64);
        ts += __shfl_xor(ts, 32, 64);
        l_reg += ts;
        bf16x8 pf;
        pf[0] = f2b(e0); pf[1] = f2b(e1); pf[2] = f2b(e2); pf[3] = f2b(e3);
        pf[4] = f2b(e4); pf[5] = f2b(e5); pf[6] = f2b(e6); pf[7] = f2b(e7);

        // (f) PV: A = V (channels x pi-permuted keys), B = pf (local pack)
        __builtin_amdgcn_s_setprio(1);
        #pragma unroll
        for (int ct = 0; ct < 16; ct++) {
            bf16x8 vv = __builtin_shufflevector(vlo[ct], vhi[ct], 0, 1, 2, 3, 4, 5, 6, 7);
            O[ct] = __builtin_amdgcn_mfma_f32_16x16x32_bf16(vv, pf, O[ct], 0, 0, 0);
        }
        __builtin_amdgcn_s_setprio(0);

        // (g) LDS-read ordering only (stage(next) stays in flight across barrier)
        asm volatile("s_waitcnt lgkmcnt(0)" ::: "memory");
        __builtin_amdgcn_s_barrier();
    }
    asm volatile("s_waitcnt vmcnt(0)" ::: "memory");   // drain dummy stage before exit

    // ---- store partial O numerators + m,l
    size_t n = (size_t)(b * NSP + sp) * NPIX + q0 + qg * 16 + ln;
    unsigned short* Ob = Opart + n * CH + cs * 256 + quad * 4;
    #pragma unroll
    for (int ct = 0; ct < 16; ct++) {
        bf16x4 pk;
        #pragma unroll
        for (int r = 0; r < 4; r++) pk[r] = f2b(O[ct][r]);
        *(bf16x4*)(Ob + ct * 16) = pk;
    }
    if (cs == 0 && quad == 0) {
        ml[n * 2 + 0] = m_reg;
        ml[n * 2 + 1] = l_reg;
    }
}

// ---------------------------------------------------------------- merge 2 splits + proj + residual
__global__ __launch_bounds__(512, 2) void merge_kernel(
    const float* __restrict__ x,
    const unsigned short* __restrict__ Opart,
    const float* __restrict__ ml,
    const unsigned short* __restrict__ pw,   // bf16 proj_w [512][512]
    const float* __restrict__ pb,
    float* __restrict__ out)
{
    __shared__ __align__(16) unsigned short ao[32][520];
    int b  = blockIdx.y;
    int q0 = blockIdx.x * 32;
    int tid = threadIdx.x;
    int wv = tid >> 6, lane = tid & 63, ln = lane & 15, quad = lane >> 4;

    {   // combine splits: p = tid&31 (pixel), cs = tid>>5 (16 slots of 8ch)
        int p = tid & 31, cs = tid >> 5;
        int n = q0 + p;
        size_t i0 = ((size_t)(b * NSP + 0) * NPIX + n) * 2;
        size_t i1 = ((size_t)(b * NSP + 1) * NPIX + n) * 2;
        float m0 = ml[i0], l0 = ml[i0 + 1];
        float m1 = ml[i1], l1 = ml[i1 + 1];
        float M  = fmaxf(m0, m1);
        float e0 = __expf(m0 - M), e1 = __expf(m1 - M);
        float den = l0 * e0 + l1 * e1;
        float w0 = e0 / den, w1 = e1 / den;
        const unsigned short* O0 = Opart + ((size_t)(b * NSP + 0) * NPIX + n) * CH;
        const unsigned short* O1 = Opart + ((size_t)(b * NSP + 1) * NPIX + n) * CH;
        #pragma unroll
        for (int k = 0; k < 4; k++) {
            int c = cs * 8 + k * 128;
            bf16x8 a0 = *(const bf16x8*)(O0 + c);
            bf16x8 a1 = *(const bf16x8*)(O1 + c);
            #pragma unroll
            for (int j = 0; j < 8; j++)
                ao[p][c + j] = f2b(b2f((unsigned short)a0[j]) * w0 +
                                   b2f((unsigned short)a1[j]) * w1);
        }
    }
    __syncthreads();

    // ---- proj: out channels [wv*64,+64) + bias + residual (fp32)
    #pragma unroll
    for (int nt = 0; nt < 4; nt++) {
        int o = wv * 64 + nt * 16 + ln;
        const unsigned short* bp = pw + (size_t)o * CH + quad * 8;
        bf16x8 wf[16];
        #pragma unroll
        for (int k = 0; k < 16; k++) wf[k] = *(const bf16x8*)(bp + k * 32);
        float bi = pb[o];
        #pragma unroll
        for (int qt = 0; qt < 2; qt++) {
            f32x4 acc = {0.f, 0.f, 0.f, 0.f};
            #pragma unroll
            for (int k = 0; k < 16; k++) {
                bf16x8 a = *(const bf16x8*)(&ao[qt * 16 + ln][quad * 8 + k * 32]);
                acc = __builtin_amdgcn_mfma_f32_16x16x32_bf16(a, wf[k], acc, 0, 0, 0);
            }
            size_t base = ((size_t)b * CH + o) * NPIX + q0 + qt * 16 + quad * 4;
            f32x4 xin = *(const f32x4*)(x + base);
            f32x4 o4;
            #pragma unroll
            for (int r = 0; r < 4; r++) o4[r] = xin[r] + acc[r] + bi;
            *(f32x4*)(out + base) = o4;
        }
    }
}

// ----------------------------------------------------------------
extern "C" void kernel_launch(void* const* d_in, const int* in_sizes, int n_in,
                              void* d_out, int out_size, void* d_ws, size_t ws_size,
                              hipStream_t stream)
{
    const float* x      = (const float*)d_in[0];
    const float* gn_g   = (const float*)d_in[1];
    const float* gn_b   = (const float*)d_in[2];
    const float* qkv_w  = (const float*)d_in[3];
    const float* qkv_b  = (const float*)d_in[4];
    const float* proj_w = (const float*)d_in[5];
    const float* proj_b = (const float*)d_in[6];
    float* out = (float*)d_out;

    // Workspace (shorts): K 4M | V 4M | Q 4M | wbf 1M | stats/part/ml | Opart 8M (~42MB)
    // hnb (4M shorts) aliases the START of Opart: written by hn_kernel, read by qkv,
    // then clobbered by attn's Opart writes (qkv complete by then; stream-serialized).
    unsigned short* ws  = (unsigned short*)d_ws;
    unsigned short* Kb  = ws;                           // [2][4096][512]
    unsigned short* Vb  = ws + 4u * 1024 * 1024;        // [2][512][4096]
    unsigned short* Qb  = ws + 8u * 1024 * 1024;        // [2][4096][512] (scaled)
    unsigned short* wbf = ws + 12u * 1024 * 1024;       // qkv_w | proj_w bf16
    unsigned short* wp  = wbf + 786432;
    float* stats = (float*)(ws + 13u * 1024 * 1024);             // 128 f32
    f32x2* part  = (f32x2*)(ws + 13u * 1024 * 1024 + 1024);      // 256 f32x2
    float* ml    = (float*)(ws + 13u * 1024 * 1024 + 4096);      // [2][2][4096][2] f32
    unsigned short* Opart = ws + 13u * 1024 * 1024 + 4096 + 131072;
    unsigned short* hnb   = Opart;                      // alias (see above)

    convert_kernel<<<dim3(1048576 / 256), 256, 0, stream>>>(qkv_w, proj_w, wbf);
    stats1_kernel <<<dim3(256), 256, 0, stream>>>(x, part);
    stats2_kernel <<<dim3(1), 64, 0, stream>>>(part, stats);
    hn_kernel     <<<dim3(2048), 256, 0, stream>>>(x, gn_g, gn_b, stats, hnb);
    qkv_kernel    <<<dim3(NPIX / 64, BATCH, 3), 256, 0, stream>>>(
        hnb, wbf, qkv_b, Qb, Kb, Vb);
    attn_kernel   <<<dim3(512), 256, 0, stream>>>(Qb, Kb, Vb, Opart, ml);
    merge_kernel  <<<dim3(NPIX / 32, BATCH), 512, 0, stream>>>(
        x, Opart, ml, wp, proj_b, out);
}

// Round 6
// 377.582 us; speedup vs baseline: 2.0359x; 2.0359x over previous
//
#include <hip/hip_runtime.h>

typedef __attribute__((ext_vector_type(8))) short bf16x8;
typedef __attribute__((ext_vector_type(4))) short bf16x4;
typedef __attribute__((ext_vector_type(4))) float f32x4;
typedef __attribute__((ext_vector_type(2))) float f32x2;

#define BATCH 2
#define CH    512
#define NPIX  4096
#define NSP   2
#define SPK   2048   // keys per split
#define KT    32     // keys per tile

__device__ __forceinline__ unsigned short f2b(float f) {
    unsigned int u; __builtin_memcpy(&u, &f, 4);
    u = u + 0x7FFFu + ((u >> 16) & 1u);   // RNE
    return (unsigned short)(u >> 16);
}
__device__ __forceinline__ float b2f(unsigned short h) {
    unsigned int u = ((unsigned int)h) << 16;
    float f; __builtin_memcpy(&f, &u, 4);
    return f;
}
// async 16B/lane global->LDS (wave-uniform LDS base, per-lane global src)
__device__ __forceinline__ void gll16(void* lds, const void* g) {
    __builtin_amdgcn_global_load_lds(
        (const __attribute__((address_space(1))) void*)g,
        (__attribute__((address_space(3))) void*)lds, 16, 0, 0);
}

// ---------------------------------------------------------------- fp32 -> bf16 weight convert
__global__ __launch_bounds__(256) void convert_kernel(
    const float* __restrict__ qkv_w, const float* __restrict__ proj_w,
    unsigned short* __restrict__ wbf)
{
    int i = blockIdx.x * 256 + threadIdx.x;            // grid covers 1048576
    float v = (i < 786432) ? qkv_w[i] : proj_w[i - 786432];
    wbf[i] = f2b(v);
}

// ---------------------------------------------------------------- GN stats (2-stage, parallel)
__global__ __launch_bounds__(256) void stats1_kernel(
    const float* __restrict__ x, f32x2* __restrict__ part)
{
    int id = blockIdx.x;            // 256 blocks: bg*4 + quarter
    int bg = id >> 2, q = id & 3;
    int b = bg >> 5, g = bg & 31;
    const float* xp = x + ((size_t)b * CH + (size_t)g * 16 + q * 4) * NPIX;
    float s = 0.f, ss = 0.f;
    for (int i = threadIdx.x; i < 4 * NPIX; i += 256) {
        float v = xp[i]; s += v; ss += v * v;
    }
    for (int off = 32; off; off >>= 1) {
        s  += __shfl_down(s,  off, 64);
        ss += __shfl_down(ss, off, 64);
    }
    __shared__ float red[2][4];
    int wv = threadIdx.x >> 6;
    if ((threadIdx.x & 63) == 0) { red[0][wv] = s; red[1][wv] = ss; }
    __syncthreads();
    if (threadIdx.x == 0) {
        s  = red[0][0] + red[0][1] + red[0][2] + red[0][3];
        ss = red[1][0] + red[1][1] + red[1][2] + red[1][3];
        part[id] = (f32x2){s, ss};
    }
}

__global__ __launch_bounds__(64) void stats2_kernel(
    const f32x2* __restrict__ part, float* __restrict__ stats)
{
    int t = threadIdx.x;            // 64 = b*32+g
    float s = 0.f, ss = 0.f;
    #pragma unroll
    for (int q = 0; q < 4; q++) { f32x2 p = part[t * 4 + q]; s += p[0]; ss += p[1]; }
    const float inv = 1.f / (16 * NPIX);
    float mean = s * inv;
    float var  = ss * inv - mean * mean;
    stats[t * 2 + 0] = mean;
    stats[t * 2 + 1] = rsqrtf(var + 1e-6f);
}

// ---------------------------------------------------------------- GroupNorm materialize (bf16)
__global__ __launch_bounds__(256) void hn_kernel(
    const float* __restrict__ x,
    const float* __restrict__ gamma, const float* __restrict__ beta,
    const float* __restrict__ stats,
    unsigned short* __restrict__ hnb)    // [b][c][n] bf16
{
    size_t i = ((size_t)blockIdx.x * 256 + threadIdx.x) * 8;   // grid 2048
    int b = (int)(i >> 21), c = (int)((i >> 12) & 511);
    float mean = stats[(b * 32 + (c >> 4)) * 2 + 0];
    float rstd = stats[(b * 32 + (c >> 4)) * 2 + 1];
    float ga = gamma[c] * rstd;
    float be = beta[c] - mean * ga;
    f32x4 v0 = *(const f32x4*)(x + i);
    f32x4 v1 = *(const f32x4*)(x + i + 4);
    bf16x8 o;
    o[0] = f2b(v0[0]*ga+be); o[1] = f2b(v0[1]*ga+be);
    o[2] = f2b(v0[2]*ga+be); o[3] = f2b(v0[3]*ga+be);
    o[4] = f2b(v1[0]*ga+be); o[5] = f2b(v1[1]*ga+be);
    o[6] = f2b(v1[2]*ga+be); o[7] = f2b(v1[3]*ga+be);
    *(bf16x8*)(hnb + i) = o;
}

// ---------------------------------------------------------------- Q/K/V GEMM (64-pixel tiles)
// grid (64, 2, 3) = 384 blocks, 2 blocks/CU. third 0->Q (scaled), 1->K, 2->V.
// V is stored PI-PERMUTED within each 32-key group: stored pos s holds key
// k(s) = (s>>3)*4 + (s&3) + 16*((s>>2)&1), so attn's PV A-fragment is one
// contiguous 16B read per lane. (Keys m..m+3 share q,h -> s stays contiguous.)
__global__ __launch_bounds__(256, 2) void qkv_kernel(
    const unsigned short* __restrict__ hnb,  // [b][c][n] bf16
    const unsigned short* __restrict__ wbf,  // bf16 qkv_w [1536][512]
    const float* __restrict__ bias,
    unsigned short* __restrict__ Q,          // [b][n][c] pre-scaled
    unsigned short* __restrict__ K,          // [b][n][c]
    unsigned short* __restrict__ V)          // [b][c][grp][32 permuted]
{
    __shared__ unsigned short hn[64][520];
    int b     = blockIdx.y;
    int third = blockIdx.z;
    int m0    = blockIdx.x * 64;
    int tid = threadIdx.x;
    {   // stage hn: p = tid&63 (pixel), cg = tid>>6 (4 channel slots)
        const unsigned short* hb = hnb + (size_t)b * CH * NPIX + m0;
        int p = tid & 63, cg = tid >> 6;
        for (int c0 = 0; c0 < CH; c0 += 4) {
            int c = c0 + cg;
            hn[p][c] = hb[(size_t)c * NPIX + p];
        }
    }
    __syncthreads();

    int wv = tid >> 6, lane = tid & 63, ln = lane & 15, quad = lane >> 4;
    const float scale = 0.04419417382415922f;  // 512^-0.5
    #pragma unroll
    for (int nt = 0; nt < 8; nt++) {
        int o = nt * 64 + wv * 16 + ln;            // [0, 512)
        int row = third * 512 + o;
        const unsigned short* bp = wbf + (size_t)row * CH + quad * 8;
        bf16x8 wf[16];
        #pragma unroll
        for (int k = 0; k < 16; k++) wf[k] = *(const bf16x8*)(bp + k * 32);
        float bi = bias[row];
        #pragma unroll
        for (int qt = 0; qt < 4; qt++) {
            f32x4 acc = {0.f, 0.f, 0.f, 0.f};
            #pragma unroll
            for (int k = 0; k < 16; k++) {
                bf16x8 a = *(const bf16x8*)(&hn[qt * 16 + ln][quad * 8 + k * 32]);
                acc = __builtin_amdgcn_mfma_f32_16x16x32_bf16(a, wf[k], acc, 0, 0, 0);
            }
            int m = m0 + qt * 16 + quad * 4;
            if (third == 0) {
                #pragma unroll
                for (int r = 0; r < 4; r++)
                    Q[((size_t)b * NPIX + m + r) * CH + o] = f2b((acc[r] + bi) * scale);
            } else if (third == 1) {
                #pragma unroll
                for (int r = 0; r < 4; r++)
                    K[((size_t)b * NPIX + m + r) * CH + o] = f2b(acc[r] + bi);
            } else {
                bf16x4 pk;
                #pragma unroll
                for (int r = 0; r < 4; r++) pk[r] = f2b(acc[r] + bi);
                int grp = m & ~31;
                int s   = ((m & 15) >> 2) * 8 + ((m >> 4) & 1) * 4;  // pi position
                *(bf16x4*)(V + ((size_t)b * CH + o) * NPIX + grp + s) = pk;
            }
        }
    }
}

// ---------------------------------------------------------------- attention: in-register flash
// 256 blocks x 512 thr (8 waves), 1 block/CU. bid&7 = XCD -> (b,sp): per-XCD
// K+V working set = 4MB (= L2). Q-tile 64: waves = 4 qgroups x 2 ch-halves.
// K AND V LDS-staged via global_load_lds (full-line txns, zero duplication):
// per wave per iter only 8 VMEM instructions.  Swapped QK^T -> in-register
// softmax (defer-max THR=8); V pre-permuted in global so PV A-frag = one
// contiguous 16B LDS read (XOR-swizzled, 8-phase minimum).
__global__ __launch_bounds__(512, 2) void attn_kernel(
    const unsigned short* __restrict__ Qg,   // [b][n][c] bf16, pre-scaled
    const unsigned short* __restrict__ Kg,   // [b][n][c]
    const unsigned short* __restrict__ Vg,   // [b][c][grp][32 perm]
    unsigned short* __restrict__ Opart,      // [b][sp][n][c] bf16 numerators
    float* __restrict__ ml)                  // [b][sp][n][2] f32
{
    // LDS 128KB: K dbuf 2x32KB ([32 keyrows][64 chunks16], chunk p holds global
    // chunk p^(row&7)); V dbuf 2x32KB ([512 chrows][4 chunks16], chunk p holds
    // global chunk p^((row>>1)&3))
    __shared__ __align__(16) char sm[131072];
    char* const KB0 = sm;
    char* const KB1 = sm + 32768;
    char* const VB0 = sm + 65536;
    char* const VB1 = sm + 98304;

    int bid = blockIdx.x;
    int xcd = bid & 7;
    int b  = (xcd >> 1) & 1;
    int sp = xcd & 1;
    int q0 = (((bid >> 3) << 1) | (xcd >> 2)) << 6;   // 64 query-tiles of 64
    int tid = threadIdx.x;
    int wv = tid >> 6, lane = tid & 63, ln = lane & 15, quad = lane >> 4;
    int qg = wv >> 1, cs = wv & 1;           // query group (16q), channel half (256c)

    const unsigned short* K = Kg + ((size_t)b * NPIX + (size_t)sp * SPK) * CH;
    const unsigned short* V = Vg + (size_t)b * CH * NPIX + (size_t)sp * SPK;
    const unsigned short* Qp = Qg + ((size_t)(b * NPIX + q0 + qg * 16)) * CH;

    // K stage: 4 rows/wave; row r: LDS chunk p holds global chunk p^(r&7)
    auto stageK = [&](char* buf, int kb) {
        #pragma unroll
        for (int j = 0; j < 4; j++) {
            int r = wv * 4 + j;
            gll16(buf + r * 1024,
                  K + (size_t)(kb + r) * CH + ((lane ^ (r & 7)) << 3));
        }
    };
    // V stage: 64 ch-rows/wave; row ch: LDS chunk p holds global chunk p^((ch>>1)&3)
    auto stageV = [&](char* buf, int kb) {
        #pragma unroll
        for (int j = 0; j < 4; j++) {
            int r0 = wv * 64 + j * 16;
            int ch = r0 + (lane >> 2);
            gll16(buf + r0 * 64,
                  V + (size_t)ch * NPIX + kb + (((lane & 3) ^ ((ch >> 1) & 3)) << 3));
        }
    };

    // ---- prologue: stage tile 0 (8 ops), persistent Q fragments (16 loads)
    stageK(KB0, 0);
    stageV(VB0, 0);
    bf16x8 qf[16];
    #pragma unroll
    for (int kt = 0; kt < 16; kt++)
        qf[kt] = *(const bf16x8*)(Qp + (size_t)ln * CH + kt * 32 + quad * 8);

    // per-lane K LDS read base (swizzle folded: chunk = (kt*4+quad)^(ln&7))
    const int BK = ln * 1024 + ((quad ^ (ln & 3)) << 4) + (((ln >> 2) & 1) << 6);
    // per-lane V LDS read offset within buffer (row = cs*256 + ct*16 + ln)
    const int BV = (cs * 256 + ln) * 64 + ((quad ^ ((ln >> 1) & 3)) << 4);

    f32x4 O[16];
    #pragma unroll
    for (int i = 0; i < 16; i++) O[i] = (f32x4){0.f, 0.f, 0.f, 0.f};
    float m_reg = -1e30f, l_reg = 0.f;

    for (int it = 0; it < SPK / KT; ++it) {
        char* const KBc = (it & 1) ? KB1 : KB0;
        char* const VBc = (it & 1) ? VB1 : VB0;
        char* const KBn = (it & 1) ? KB0 : KB1;
        char* const VBn = (it & 1) ? VB0 : VB1;
        int nkb = ((it + 1) * KT) & (SPK - 1);   // last iter wraps: harmless dummy

        // (a) async-stage next tile: 8 gll16/wave, in flight across whole iter
        stageK(KBn, nkb);
        stageV(VBn, nkb);

        // (b) queue/wave = [stage(cur) 8][stage(next) 8]; vmcnt(8) ==> cur landed
        asm volatile("s_waitcnt vmcnt(8)" ::: "memory");
        __builtin_amdgcn_s_barrier();

        // (c) S = mfma(K, Q): lane -> query qg*16+ln; Sa keys quad*4+r, Sb 16+..
        const char* kE = KBc + BK;
        const char* kO = KBc + (BK ^ 64);
        f32x4 Sa = {0.f,0.f,0.f,0.f}, Sb = {0.f,0.f,0.f,0.f};
        __builtin_amdgcn_s_setprio(1);
        #pragma unroll
        for (int kt = 0; kt < 16; kt++) {
            const char* p = (kt & 1) ? kO : kE;
            bf16x8 k0 = *(const bf16x8*)(p + (kt >> 1) * 128);
            bf16x8 k1 = *(const bf16x8*)(p + (kt >> 1) * 128 + 16384);
            Sa = __builtin_amdgcn_mfma_f32_16x16x32_bf16(k0, qf[kt], Sa, 0, 0, 0);
            Sb = __builtin_amdgcn_mfma_f32_16x16x32_bf16(k1, qf[kt], Sb, 0, 0, 0);
        }
        __builtin_amdgcn_s_setprio(0);

        // (d) in-register online softmax with defer-max (THR=8)
        float mx = fmaxf(fmaxf(fmaxf(Sa[0],Sa[1]), fmaxf(Sa[2],Sa[3])),
                         fmaxf(fmaxf(Sb[0],Sb[1]), fmaxf(Sb[2],Sb[3])));
        mx = fmaxf(mx, __shfl_xor(mx, 16, 64));
        mx = fmaxf(mx, __shfl_xor(mx, 32, 64));
        if (!__all(mx <= m_reg + 8.f)) {
            float mnew  = fmaxf(m_reg, mx);
            float alpha = __expf(m_reg - mnew);
            l_reg *= alpha;
            #pragma unroll
            for (int ct = 0; ct < 16; ct++) {
                #pragma unroll
                for (int r = 0; r < 4; r++) O[ct][r] *= alpha;
            }
            m_reg = mnew;
        }
        float e0 = __expf(Sa[0]-m_reg), e1 = __expf(Sa[1]-m_reg);
        float e2 = __expf(Sa[2]-m_reg), e3 = __expf(Sa[3]-m_reg);
        float e4 = __expf(Sb[0]-m_reg), e5 = __expf(Sb[1]-m_reg);
        float e6 = __expf(Sb[2]-m_reg), e7 = __expf(Sb[3]-m_reg);
        float ts = ((e0+e1)+(e2+e3)) + ((e4+e5)+(e6+e7));
        ts += __shfl_xor(ts, 16, 64);
        ts += __shfl_xor(ts, 32, 64);
        l_reg += ts;
        bf16x8 pf;
        pf[0] = f2b(e0); pf[1] = f2b(e1); pf[2] = f2b(e2); pf[3] = f2b(e3);
        pf[4] = f2b(e4); pf[5] = f2b(e5); pf[6] = f2b(e6); pf[7] = f2b(e7);

        // (e) PV: A = V-frag (one 16B LDS read), B = pf (local pack)
        const char* vp = VBc + BV;
        __builtin_amdgcn_s_setprio(1);
        #pragma unroll
        for (int ct = 0; ct < 16; ct++) {
            bf16x8 vv = *(const bf16x8*)(vp + ct * 1024);
            O[ct] = __builtin_amdgcn_mfma_f32_16x16x32_bf16(vv, pf, O[ct], 0, 0, 0);
        }
        __builtin_amdgcn_s_setprio(0);

        // (f) all LDS reads of cur done before next iter's stage overwrites
        asm volatile("s_waitcnt lgkmcnt(0)" ::: "memory");
        __builtin_amdgcn_s_barrier();
    }
    asm volatile("s_waitcnt vmcnt(0)" ::: "memory");   // drain dummy stage before exit

    // ---- store partial O numerators + m,l
    size_t n = (size_t)(b * NSP + sp) * NPIX + q0 + qg * 16 + ln;
    unsigned short* Ob = Opart + n * CH + cs * 256 + quad * 4;
    #pragma unroll
    for (int ct = 0; ct < 16; ct++) {
        bf16x4 pk;
        #pragma unroll
        for (int r = 0; r < 4; r++) pk[r] = f2b(O[ct][r]);
        *(bf16x4*)(Ob + ct * 16) = pk;
    }
    if (cs == 0 && quad == 0) {
        ml[n * 2 + 0] = m_reg;
        ml[n * 2 + 1] = l_reg;
    }
}

// ---------------------------------------------------------------- merge 2 splits + proj + residual
__global__ __launch_bounds__(512, 2) void merge_kernel(
    const float* __restrict__ x,
    const unsigned short* __restrict__ Opart,
    const float* __restrict__ ml,
    const unsigned short* __restrict__ pw,   // bf16 proj_w [512][512]
    const float* __restrict__ pb,
    float* __restrict__ out)
{
    __shared__ __align__(16) unsigned short ao[32][520];
    int b  = blockIdx.y;
    int q0 = blockIdx.x * 32;
    int tid = threadIdx.x;
    int wv = tid >> 6, lane = tid & 63, ln = lane & 15, quad = lane >> 4;

    {   // combine splits: p = tid&31 (pixel), cs = tid>>5 (16 slots of 8ch)
        int p = tid & 31, cs = tid >> 5;
        int n = q0 + p;
        size_t i0 = ((size_t)(b * NSP + 0) * NPIX + n) * 2;
        size_t i1 = ((size_t)(b * NSP + 1) * NPIX + n) * 2;
        float m0 = ml[i0], l0 = ml[i0 + 1];
        float m1 = ml[i1], l1 = ml[i1 + 1];
        float M  = fmaxf(m0, m1);
        float e0 = __expf(m0 - M), e1 = __expf(m1 - M);
        float den = l0 * e0 + l1 * e1;
        float w0 = e0 / den, w1 = e1 / den;
        const unsigned short* O0 = Opart + ((size_t)(b * NSP + 0) * NPIX + n) * CH;
        const unsigned short* O1 = Opart + ((size_t)(b * NSP + 1) * NPIX + n) * CH;
        #pragma unroll
        for (int k = 0; k < 4; k++) {
            int c = cs * 8 + k * 128;
            bf16x8 a0 = *(const bf16x8*)(O0 + c);
            bf16x8 a1 = *(const bf16x8*)(O1 + c);
            #pragma unroll
            for (int j = 0; j < 8; j++)
                ao[p][c + j] = f2b(b2f((unsigned short)a0[j]) * w0 +
                                   b2f((unsigned short)a1[j]) * w1);
        }
    }
    __syncthreads();

    // ---- proj: out channels [wv*64,+64) + bias + residual (fp32)
    #pragma unroll
    for (int nt = 0; nt < 4; nt++) {
        int o = wv * 64 + nt * 16 + ln;
        const unsigned short* bp = pw + (size_t)o * CH + quad * 8;
        bf16x8 wf[16];
        #pragma unroll
        for (int k = 0; k < 16; k++) wf[k] = *(const bf16x8*)(bp + k * 32);
        float bi = pb[o];
        #pragma unroll
        for (int qt = 0; qt < 2; qt++) {
            f32x4 acc = {0.f, 0.f, 0.f, 0.f};
            #pragma unroll
            for (int k = 0; k < 16; k++) {
                bf16x8 a = *(const bf16x8*)(&ao[qt * 16 + ln][quad * 8 + k * 32]);
                acc = __builtin_amdgcn_mfma_f32_16x16x32_bf16(a, wf[k], acc, 0, 0, 0);
            }
            size_t base = ((size_t)b * CH + o) * NPIX + q0 + qt * 16 + quad * 4;
            f32x4 xin = *(const f32x4*)(x + base);
            f32x4 o4;
            #pragma unroll
            for (int r = 0; r < 4; r++) o4[r] = xin[r] + acc[r] + bi;
            *(f32x4*)(out + base) = o4;
        }
    }
}

// ----------------------------------------------------------------
extern "C" void kernel_launch(void* const* d_in, const int* in_sizes, int n_in,
                              void* d_out, int out_size, void* d_ws, size_t ws_size,
                              hipStream_t stream)
{
    const float* x      = (const float*)d_in[0];
    const float* gn_g   = (const float*)d_in[1];
    const float* gn_b   = (const float*)d_in[2];
    const float* qkv_w  = (const float*)d_in[3];
    const float* qkv_b  = (const float*)d_in[4];
    const float* proj_w = (const float*)d_in[5];
    const float* proj_b = (const float*)d_in[6];
    float* out = (float*)d_out;

    // Workspace (shorts): K 4M | V 4M | Q 4M | wbf 1M | stats/part/ml | Opart 8M (~42MB)
    // hnb (4M shorts) aliases the START of Opart: written by hn_kernel, read by qkv,
    // then clobbered by attn's Opart writes (qkv complete by then; stream-serialized).
    unsigned short* ws  = (unsigned short*)d_ws;
    unsigned short* Kb  = ws;                           // [2][4096][512]
    unsigned short* Vb  = ws + 4u * 1024 * 1024;        // [2][512][4096] (pi-permuted groups)
    unsigned short* Qb  = ws + 8u * 1024 * 1024;        // [2][4096][512] (scaled)
    unsigned short* wbf = ws + 12u * 1024 * 1024;       // qkv_w | proj_w bf16
    unsigned short* wp  = wbf + 786432;
    float* stats = (float*)(ws + 13u * 1024 * 1024);             // 128 f32
    f32x2* part  = (f32x2*)(ws + 13u * 1024 * 1024 + 1024);      // 256 f32x2
    float* ml    = (float*)(ws + 13u * 1024 * 1024 + 4096);      // [2][2][4096][2] f32
    unsigned short* Opart = ws + 13u * 1024 * 1024 + 4096 + 131072;
    unsigned short* hnb   = Opart;                      // alias (see above)

    convert_kernel<<<dim3(1048576 / 256), 256, 0, stream>>>(qkv_w, proj_w, wbf);
    stats1_kernel <<<dim3(256), 256, 0, stream>>>(x, part);
    stats2_kernel <<<dim3(1), 64, 0, stream>>>(part, stats);
    hn_kernel     <<<dim3(2048), 256, 0, stream>>>(x, gn_g, gn_b, stats, hnb);
    qkv_kernel    <<<dim3(NPIX / 64, BATCH, 3), 256, 0, stream>>>(
        hnb, wbf, qkv_b, Qb, Kb, Vb);
    attn_kernel   <<<dim3(256), 512, 0, stream>>>(Qb, Kb, Vb, Opart, ml);
    merge_kernel  <<<dim3(NPIX / 32, BATCH), 512, 0, stream>>>(
        x, Opart, ml, wp, proj_b, out);
}

// Round 7
// 348.078 us; speedup vs baseline: 2.2084x; 1.0848x over previous
//
#include <hip/hip_runtime.h>

typedef __attribute__((ext_vector_type(8))) short bf16x8;
typedef __attribute__((ext_vector_type(4))) short bf16x4;
typedef __attribute__((ext_vector_type(4))) float f32x4;
typedef __attribute__((ext_vector_type(2))) float f32x2;

#define BATCH 2
#define CH    512
#define NPIX  4096
#define NSP   2
#define SPK   2048   // keys per split
#define KT    32     // keys per tile

__device__ __forceinline__ unsigned short f2b(float f) {
    unsigned int u; __builtin_memcpy(&u, &f, 4);
    u = u + 0x7FFFu + ((u >> 16) & 1u);   // RNE
    return (unsigned short)(u >> 16);
}
__device__ __forceinline__ float b2f(unsigned short h) {
    unsigned int u = ((unsigned int)h) << 16;
    float f; __builtin_memcpy(&f, &u, 4);
    return f;
}
// async 16B/lane global->LDS (wave-uniform LDS base, per-lane global src)
__device__ __forceinline__ void gll16(void* lds, const void* g) {
    __builtin_amdgcn_global_load_lds(
        (const __attribute__((address_space(1))) void*)g,
        (__attribute__((address_space(3))) void*)lds, 16, 0, 0);
}

// ---------------------------------------------------------------- fp32 -> bf16 weight convert
__global__ __launch_bounds__(256) void convert_kernel(
    const float* __restrict__ qkv_w, const float* __restrict__ proj_w,
    unsigned short* __restrict__ wbf)
{
    int i = blockIdx.x * 256 + threadIdx.x;            // grid covers 1048576
    float v = (i < 786432) ? qkv_w[i] : proj_w[i - 786432];
    wbf[i] = f2b(v);
}

// ---------------------------------------------------------------- GN stats (2-stage, parallel)
__global__ __launch_bounds__(256) void stats1_kernel(
    const float* __restrict__ x, f32x2* __restrict__ part)
{
    int id = blockIdx.x;            // 256 blocks: bg*4 + quarter
    int bg = id >> 2, q = id & 3;
    int b = bg >> 5, g = bg & 31;
    const float* xp = x + ((size_t)b * CH + (size_t)g * 16 + q * 4) * NPIX;
    float s = 0.f, ss = 0.f;
    for (int i = threadIdx.x; i < 4 * NPIX; i += 256) {
        float v = xp[i]; s += v; ss += v * v;
    }
    for (int off = 32; off; off >>= 1) {
        s  += __shfl_down(s,  off, 64);
        ss += __shfl_down(ss, off, 64);
    }
    __shared__ float red[2][4];
    int wv = threadIdx.x >> 6;
    if ((threadIdx.x & 63) == 0) { red[0][wv] = s; red[1][wv] = ss; }
    __syncthreads();
    if (threadIdx.x == 0) {
        s  = red[0][0] + red[0][1] + red[0][2] + red[0][3];
        ss = red[1][0] + red[1][1] + red[1][2] + red[1][3];
        part[id] = (f32x2){s, ss};
    }
}

__global__ __launch_bounds__(64) void stats2_kernel(
    const f32x2* __restrict__ part, float* __restrict__ stats)
{
    int t = threadIdx.x;            // 64 = b*32+g
    float s = 0.f, ss = 0.f;
    #pragma unroll
    for (int q = 0; q < 4; q++) { f32x2 p = part[t * 4 + q]; s += p[0]; ss += p[1]; }
    const float inv = 1.f / (16 * NPIX);
    float mean = s * inv;
    float var  = ss * inv - mean * mean;
    stats[t * 2 + 0] = mean;
    stats[t * 2 + 1] = rsqrtf(var + 1e-6f);
}

// ---------------------------------------------------------------- Q/K/V GEMM + fused GroupNorm
// grid (64, 2, 3) = 384 blocks, 2 blocks/CU. third 0->Q (scaled), 1->K, 2->V.
// GN fused into the staging pass (vectorized f32x4 reads of x).
// V stored PI-PERMUTED within each 32-key group: stored pos s holds key
// k(s) = (s>>3)*4 + (s&3) + 16*((s>>2)&1) -> attn PV A-frag = one 16B read.
__global__ __launch_bounds__(256, 2) void qkv_kernel(
    const float* __restrict__ x,
    const unsigned short* __restrict__ wbf,  // bf16 qkv_w [1536][512]
    const float* __restrict__ bias,
    const float* __restrict__ gamma,
    const float* __restrict__ beta,
    const float* __restrict__ stats,
    unsigned short* __restrict__ Q,          // [b][n][c] pre-scaled
    unsigned short* __restrict__ K,          // [b][n][c]
    unsigned short* __restrict__ V)          // [b][c][grp][32 permuted]
{
    __shared__ unsigned short hn[64][520];
    int b     = blockIdx.y;
    int third = blockIdx.z;
    int m0    = blockIdx.x * 64;
    int tid = threadIdx.x;
    {   // stage + normalize: p4 = (tid&15)*4 (4 pixels), cg = tid>>4 (16 ch slots)
        const float* xb = x + (size_t)b * CH * NPIX + m0;
        const float* st = stats + b * 64;
        int p4 = (tid & 15) * 4, cg = tid >> 4;
        for (int c0 = 0; c0 < CH; c0 += 16) {
            int c = c0 + cg;
            float mean = st[(c >> 4) * 2 + 0];
            float rstd = st[(c >> 4) * 2 + 1];
            float ga = gamma[c] * rstd;
            float be = beta[c] - mean * ga;
            f32x4 v = *(const f32x4*)(xb + (size_t)c * NPIX + p4);
            hn[p4 + 0][c] = f2b(v[0] * ga + be);
            hn[p4 + 1][c] = f2b(v[1] * ga + be);
            hn[p4 + 2][c] = f2b(v[2] * ga + be);
            hn[p4 + 3][c] = f2b(v[3] * ga + be);
        }
    }
    __syncthreads();

    int wv = tid >> 6, lane = tid & 63, ln = lane & 15, quad = lane >> 4;
    const float scale = 0.04419417382415922f;  // 512^-0.5
    #pragma unroll
    for (int nt = 0; nt < 8; nt++) {
        int o = nt * 64 + wv * 16 + ln;            // [0, 512)
        int row = third * 512 + o;
        const unsigned short* bp = wbf + (size_t)row * CH + quad * 8;
        bf16x8 wf[16];
        #pragma unroll
        for (int k = 0; k < 16; k++) wf[k] = *(const bf16x8*)(bp + k * 32);
        float bi = bias[row];
        #pragma unroll
        for (int qt = 0; qt < 4; qt++) {
            f32x4 acc = {0.f, 0.f, 0.f, 0.f};
            #pragma unroll
            for (int k = 0; k < 16; k++) {
                bf16x8 a = *(const bf16x8*)(&hn[qt * 16 + ln][quad * 8 + k * 32]);
                acc = __builtin_amdgcn_mfma_f32_16x16x32_bf16(a, wf[k], acc, 0, 0, 0);
            }
            int m = m0 + qt * 16 + quad * 4;
            if (third == 0) {
                #pragma unroll
                for (int r = 0; r < 4; r++)
                    Q[((size_t)b * NPIX + m + r) * CH + o] = f2b((acc[r] + bi) * scale);
            } else if (third == 1) {
                #pragma unroll
                for (int r = 0; r < 4; r++)
                    K[((size_t)b * NPIX + m + r) * CH + o] = f2b(acc[r] + bi);
            } else {
                bf16x4 pk;
                #pragma unroll
                for (int r = 0; r < 4; r++) pk[r] = f2b(acc[r] + bi);
                int grp = m & ~31;
                int s   = ((m & 15) >> 2) * 8 + ((m >> 4) & 1) * 4;  // pi position
                *(bf16x4*)(V + ((size_t)b * CH + o) * NPIX + grp + s) = pk;
            }
        }
    }
}

// ---------------------------------------------------------------- attention: in-register flash
// 256 blocks x 512 thr (8 waves), 1 block/CU. bid&7 = XCD -> (b,sp).
// Wave (qg,cs): 16 queries (qg), 256-ch half (cs).  S computed as PARTIALS over
// the wave's ch-half (qf = 8 frags -> 32 VGPR, forces Q residency; K LDS reads
// halve; no redundant S-MFMA), then the cs-pair exchanges partials through a
// 16KB LDS buffer and adds.  In-register softmax (defer-max THR=8).  V single-
// buffered in LDS (32KB), staged at iter end, gated by vmcnt(4)+barrier before
// PV.  3 barriers/iter, counted vmcnt only (8 for K, 4 for V), no drain-0.
__global__ __launch_bounds__(512, 2) void attn_kernel(
    const unsigned short* __restrict__ Qg,   // [b][n][c] bf16, pre-scaled
    const unsigned short* __restrict__ Kg,   // [b][n][c]
    const unsigned short* __restrict__ Vg,   // [b][c][grp][32 perm]
    unsigned short* __restrict__ Opart,      // [b][sp][n][c] bf16 numerators
    float* __restrict__ ml)                  // [b][sp][n][2] f32
{
    // LDS 112KB: K dbuf 2x32K @0 ([32 keyrows][64 chunks16], chunk p holds
    // global chunk p^(row&7)); V 32K @65536 ([512 chrows][4 chunks16], chunk p
    // holds global chunk p^((row>>1)&3)); Sx 16K @98304 (cs-pair S exchange).
    __shared__ __align__(16) char sm[114688];
    char* const KB0 = sm;
    char* const KB1 = sm + 32768;
    char* const VB  = sm + 65536;
    char* const SX  = sm + 98304;

    int bid = blockIdx.x;
    int xcd = bid & 7;
    int b  = (xcd >> 1) & 1;
    int sp = xcd & 1;
    int q0 = (((bid >> 3) << 1) | (xcd >> 2)) << 6;   // 64-query tiles
    int tid = threadIdx.x;
    int wv = tid >> 6, lane = tid & 63, ln = lane & 15, quad = lane >> 4;
    int qg = wv >> 1, cs = wv & 1;           // query group (16q), channel half (256c)

    const unsigned short* K = Kg + ((size_t)b * NPIX + (size_t)sp * SPK) * CH;
    const unsigned short* V = Vg + (size_t)b * CH * NPIX + (size_t)sp * SPK;
    const unsigned short* Qp = Qg + ((size_t)(b * NPIX + q0 + qg * 16)) * CH;

    // K stage: 4 rows/wave; row r: LDS chunk p holds global chunk p^(r&7)
    auto stageK = [&](char* buf, int kb) {
        #pragma unroll
        for (int j = 0; j < 4; j++) {
            int r = wv * 4 + j;
            gll16(buf + r * 1024,
                  K + (size_t)(kb + r) * CH + ((lane ^ (r & 7)) << 3));
        }
    };
    // V stage: 64 ch-rows/wave; row ch: LDS chunk p holds global chunk p^((ch>>1)&3)
    auto stageV = [&](int kb) {
        #pragma unroll
        for (int j = 0; j < 4; j++) {
            int r0 = wv * 64 + j * 16;
            int ch = r0 + (lane >> 2);
            gll16(VB + r0 * 64,
                  V + (size_t)ch * NPIX + kb + (((lane & 3) ^ ((ch >> 1) & 3)) << 3));
        }
    };

    // ---- prologue: K(0), qf (8 frags: this wave's ch-half only), V(0)
    stageK(KB0, 0);
    bf16x8 qf[8];
    #pragma unroll
    for (int kt = 0; kt < 8; kt++)
        qf[kt] = *(const bf16x8*)(Qp + (size_t)ln * CH + cs * 256 + kt * 32 + quad * 8);
    stageV(0);

    // K LDS read base (swizzle folded; + cs half offset cs*4*128)
    const int BK = ln * 1024 + ((quad ^ (ln & 3)) << 4) + (((ln >> 2) & 1) << 6) + cs * 512;
    // V LDS read base (row = cs*256 + ct*16 + ln)
    const int BV = (cs * 256 + ln) * 64 + ((quad ^ ((ln >> 1) & 3)) << 4);
    // Sx: lane slot = 32B at row (wv*16+ln); balanced groups via quad^(ln&3), p=(ln>>2)&1
    const int sxo = ((quad ^ (ln & 3)) << 5) + (((ln >> 2) & 1) << 4);
    const int sxw = ((wv * 16 + ln) << 7) + sxo;         // own slot
    const int sxr = (((wv ^ 1) * 16 + ln) << 7) + sxo;   // partner slot (cs flipped)

    f32x4 O[16];
    #pragma unroll
    for (int i = 0; i < 16; i++) O[i] = (f32x4){0.f, 0.f, 0.f, 0.f};
    float m_reg = -1e30f, l_reg = 0.f;

    for (int it = 0; it < SPK / KT; ++it) {
        char* const KBc = (it & 1) ? KB1 : KB0;
        char* const KBn = (it & 1) ? KB0 : KB1;
        int nkb = ((it + 1) * KT) & (SPK - 1);   // last iter wraps: harmless dummy

        // (1) stage next K tile (in flight across the whole iteration)
        stageK(KBn, nkb);

        // (2) queue = [K(it) 4][V(it) 4][K(it+1) 4]; vmcnt(8) ==> K(it) landed
        asm volatile("s_waitcnt vmcnt(8)" ::: "memory");
        __builtin_amdgcn_s_barrier();

        // (3) S partial = mfma(K, Q) over this wave's 256-ch half
        const char* kE = KBc + BK;
        const char* kO = KBc + (BK ^ 64);
        f32x4 Sa = {0.f,0.f,0.f,0.f}, Sb = {0.f,0.f,0.f,0.f};
        __builtin_amdgcn_s_setprio(1);
        #pragma unroll
        for (int kt = 0; kt < 8; kt++) {
            const char* p = (kt & 1) ? kO : kE;
            bf16x8 k0 = *(const bf16x8*)(p + (kt >> 1) * 128);
            bf16x8 k1 = *(const bf16x8*)(p + (kt >> 1) * 128 + 16384);
            Sa = __builtin_amdgcn_mfma_f32_16x16x32_bf16(k0, qf[kt], Sa, 0, 0, 0);
            Sb = __builtin_amdgcn_mfma_f32_16x16x32_bf16(k1, qf[kt], Sb, 0, 0, 0);
        }
        __builtin_amdgcn_s_setprio(0);

        // (4) exchange partials with cs-partner; also gate V(it) for ALL waves
        *(f32x4*)(SX + sxw)        = Sa;
        *(f32x4*)(SX + (sxw ^ 16)) = Sb;
        asm volatile("s_waitcnt vmcnt(4) lgkmcnt(0)" ::: "memory");
        __builtin_amdgcn_s_barrier();
        Sa += *(const f32x4*)(SX + sxr);
        Sb += *(const f32x4*)(SX + (sxr ^ 16));

        // (5) in-register online softmax with defer-max (THR=8)
        float mx = fmaxf(fmaxf(fmaxf(Sa[0],Sa[1]), fmaxf(Sa[2],Sa[3])),
                         fmaxf(fmaxf(Sb[0],Sb[1]), fmaxf(Sb[2],Sb[3])));
        mx = fmaxf(mx, __shfl_xor(mx, 16, 64));
        mx = fmaxf(mx, __shfl_xor(mx, 32, 64));
        if (!__all(mx <= m_reg + 8.f)) {
            float mnew  = fmaxf(m_reg, mx);
            float alpha = __expf(m_reg - mnew);
            l_reg *= alpha;
            #pragma unroll
            for (int ct = 0; ct < 16; ct++) {
                #pragma unroll
                for (int r = 0; r < 4; r++) O[ct][r] *= alpha;
            }
            m_reg = mnew;
        }
        float e0 = __expf(Sa[0]-m_reg), e1 = __expf(Sa[1]-m_reg);
        float e2 = __expf(Sa[2]-m_reg), e3 = __expf(Sa[3]-m_reg);
        float e4 = __expf(Sb[0]-m_reg), e5 = __expf(Sb[1]-m_reg);
        float e6 = __expf(Sb[2]-m_reg), e7 = __expf(Sb[3]-m_reg);
        float ts = ((e0+e1)+(e2+e3)) + ((e4+e5)+(e6+e7));
        ts += __shfl_xor(ts, 16, 64);
        ts += __shfl_xor(ts, 32, 64);
        l_reg += ts;
        bf16x8 pf;
        pf[0] = f2b(e0); pf[1] = f2b(e1); pf[2] = f2b(e2); pf[3] = f2b(e3);
        pf[4] = f2b(e4); pf[5] = f2b(e5); pf[6] = f2b(e6); pf[7] = f2b(e7);

        // (6) PV: A = V-frag (one 16B LDS read), B = pf (local pack)
        const char* vp = VB + BV;
        __builtin_amdgcn_s_setprio(1);
        #pragma unroll
        for (int ct = 0; ct < 16; ct++) {
            bf16x8 vv = *(const bf16x8*)(vp + ct * 1024);
            O[ct] = __builtin_amdgcn_mfma_f32_16x16x32_bf16(vv, pf, O[ct], 0, 0, 0);
        }
        __builtin_amdgcn_s_setprio(0);

        // (7) all waves' V reads done -> safe to overwrite VB
        asm volatile("s_waitcnt lgkmcnt(0)" ::: "memory");
        __builtin_amdgcn_s_barrier();

        // (8) stage next V tile into the single buffer
        stageV(nkb);
    }
    asm volatile("s_waitcnt vmcnt(0)" ::: "memory");   // drain dummy stages before exit

    // ---- store partial O numerators + m,l
    size_t n = (size_t)(b * NSP + sp) * NPIX + q0 + qg * 16 + ln;
    unsigned short* Ob = Opart + n * CH + cs * 256 + quad * 4;
    #pragma unroll
    for (int ct = 0; ct < 16; ct++) {
        bf16x4 pk;
        #pragma unroll
        for (int r = 0; r < 4; r++) pk[r] = f2b(O[ct][r]);
        *(bf16x4*)(Ob + ct * 16) = pk;
    }
    if (cs == 0 && quad == 0) {
        ml[n * 2 + 0] = m_reg;
        ml[n * 2 + 1] = l_reg;
    }
}

// ---------------------------------------------------------------- merge 2 splits + proj + residual
__global__ __launch_bounds__(512, 2) void merge_kernel(
    const float* __restrict__ x,
    const unsigned short* __restrict__ Opart,
    const float* __restrict__ ml,
    const unsigned short* __restrict__ pw,   // bf16 proj_w [512][512]
    const float* __restrict__ pb,
    float* __restrict__ out)
{
    __shared__ __align__(16) unsigned short ao[32][520];
    int b  = blockIdx.y;
    int q0 = blockIdx.x * 32;
    int tid = threadIdx.x;
    int wv = tid >> 6, lane = tid & 63, ln = lane & 15, quad = lane >> 4;

    {   // combine splits: p = tid&31 (pixel), cs = tid>>5 (16 slots of 8ch)
        int p = tid & 31, cs = tid >> 5;
        int n = q0 + p;
        size_t i0 = ((size_t)(b * NSP + 0) * NPIX + n) * 2;
        size_t i1 = ((size_t)(b * NSP + 1) * NPIX + n) * 2;
        float m0 = ml[i0], l0 = ml[i0 + 1];
        float m1 = ml[i1], l1 = ml[i1 + 1];
        float M  = fmaxf(m0, m1);
        float e0 = __expf(m0 - M), e1 = __expf(m1 - M);
        float den = l0 * e0 + l1 * e1;
        float w0 = e0 / den, w1 = e1 / den;
        const unsigned short* O0 = Opart + ((size_t)(b * NSP + 0) * NPIX + n) * CH;
        const unsigned short* O1 = Opart + ((size_t)(b * NSP + 1) * NPIX + n) * CH;
        #pragma unroll
        for (int k = 0; k < 4; k++) {
            int c = cs * 8 + k * 128;
            bf16x8 a0 = *(const bf16x8*)(O0 + c);
            bf16x8 a1 = *(const bf16x8*)(O1 + c);
            #pragma unroll
            for (int j = 0; j < 8; j++)
                ao[p][c + j] = f2b(b2f((unsigned short)a0[j]) * w0 +
                                   b2f((unsigned short)a1[j]) * w1);
        }
    }
    __syncthreads();

    // ---- proj: out channels [wv*64,+64) + bias + residual (fp32)
    #pragma unroll
    for (int nt = 0; nt < 4; nt++) {
        int o = wv * 64 + nt * 16 + ln;
        const unsigned short* bp = pw + (size_t)o * CH + quad * 8;
        bf16x8 wf[16];
        #pragma unroll
        for (int k = 0; k < 16; k++) wf[k] = *(const bf16x8*)(bp + k * 32);
        float bi = pb[o];
        #pragma unroll
        for (int qt = 0; qt < 2; qt++) {
            f32x4 acc = {0.f, 0.f, 0.f, 0.f};
            #pragma unroll
            for (int k = 0; k < 16; k++) {
                bf16x8 a = *(const bf16x8*)(&ao[qt * 16 + ln][quad * 8 + k * 32]);
                acc = __builtin_amdgcn_mfma_f32_16x16x32_bf16(a, wf[k], acc, 0, 0, 0);
            }
            size_t base = ((size_t)b * CH + o) * NPIX + q0 + qt * 16 + quad * 4;
            f32x4 xin = *(const f32x4*)(x + base);
            f32x4 o4;
            #pragma unroll
            for (int r = 0; r < 4; r++) o4[r] = xin[r] + acc[r] + bi;
            *(f32x4*)(out + base) = o4;
        }
    }
}

// ----------------------------------------------------------------
extern "C" void kernel_launch(void* const* d_in, const int* in_sizes, int n_in,
                              void* d_out, int out_size, void* d_ws, size_t ws_size,
                              hipStream_t stream)
{
    const float* x      = (const float*)d_in[0];
    const float* gn_g   = (const float*)d_in[1];
    const float* gn_b   = (const float*)d_in[2];
    const float* qkv_w  = (const float*)d_in[3];
    const float* qkv_b  = (const float*)d_in[4];
    const float* proj_w = (const float*)d_in[5];
    const float* proj_b = (const float*)d_in[6];
    float* out = (float*)d_out;

    // Workspace (shorts): K 4M | V 4M | Q 4M | wbf 1M | stats/part/ml | Opart 8M (~42MB)
    unsigned short* ws  = (unsigned short*)d_ws;
    unsigned short* Kb  = ws;                           // [2][4096][512]
    unsigned short* Vb  = ws + 4u * 1024 * 1024;        // [2][512][4096] (pi-permuted groups)
    unsigned short* Qb  = ws + 8u * 1024 * 1024;        // [2][4096][512] (scaled)
    unsigned short* wbf = ws + 12u * 1024 * 1024;       // qkv_w | proj_w bf16
    unsigned short* wp  = wbf + 786432;
    float* stats = (float*)(ws + 13u * 1024 * 1024);             // 128 f32
    f32x2* part  = (f32x2*)(ws + 13u * 1024 * 1024 + 1024);      // 256 f32x2
    float* ml    = (float*)(ws + 13u * 1024 * 1024 + 4096);      // [2][2][4096][2] f32
    unsigned short* Opart = ws + 13u * 1024 * 1024 + 4096 + 131072;

    convert_kernel<<<dim3(1048576 / 256), 256, 0, stream>>>(qkv_w, proj_w, wbf);
    stats1_kernel <<<dim3(256), 256, 0, stream>>>(x, part);
    stats2_kernel <<<dim3(1), 64, 0, stream>>>(part, stats);
    qkv_kernel    <<<dim3(NPIX / 64, BATCH, 3), 256, 0, stream>>>(
        x, wbf, qkv_b, gn_g, gn_b, stats, Qb, Kb, Vb);
    attn_kernel   <<<dim3(256), 512, 0, stream>>>(Qb, Kb, Vb, Opart, ml);
    merge_kernel  <<<dim3(NPIX / 32, BATCH), 512, 0, stream>>>(
        x, Opart, ml, wp, proj_b, out);
}